// Round 2
// baseline (263.782 us; speedup 1.0000x reference)
//
#include <hip/hip_runtime.h>
#include <hip/hip_bf16.h>

#define Bdim 2
#define Tdim 4096
#define Ddim 2048
#define Hdim 4
#define DIdim 64
#define NQ 256          // H*DI
#define NCAT 324        // 256 + 64 + 4
#define NPAD 384        // padded N for the projection GEMM
#define Mdim 8192       // B*T

typedef __attribute__((ext_vector_type(8))) short bf16x8;
typedef __attribute__((ext_vector_type(4))) float f32x4;

__device__ __forceinline__ unsigned short f2bf(float f) {
    unsigned int u = __builtin_bit_cast(unsigned int, f);
    u += 0x7fffu + ((u >> 16) & 1u);          // round-to-nearest-even
    return (unsigned short)(u >> 16);
}
__device__ __forceinline__ float bf2f(unsigned short h) {
    unsigned int u = ((unsigned int)h) << 16;
    return __builtin_bit_cast(float, u);
}

// async 16B global->LDS (direct-to-LDS DMA; dest = wave-uniform base + lane*16)
__device__ __forceinline__ void gload16(const void* g, void* l) {
    __builtin_amdgcn_global_load_lds(
        (const __attribute__((address_space(1))) unsigned int*)g,
        (__attribute__((address_space(3))) unsigned int*)l, 16, 0, 0);
}

// ---------------------------------------------------------------------------
// Kernel 0: x f32 -> bf16 (one-time), 100MB traffic, BW-bound
// ---------------------------------------------------------------------------
__global__ __launch_bounds__(256) void convert_x(const float* __restrict__ x,
                                                 unsigned short* __restrict__ xb) {
    const size_t N8 = (size_t)Mdim * Ddim / 8;
    for (size_t u = (size_t)blockIdx.x * 256 + threadIdx.x; u < N8;
         u += (size_t)gridDim.x * 256) {
        const float4 v0 = *reinterpret_cast<const float4*>(&x[u * 8]);
        const float4 v1 = *reinterpret_cast<const float4*>(&x[u * 8 + 4]);
        uint4 o;
        o.x = (unsigned int)f2bf(v0.x) | ((unsigned int)f2bf(v0.y) << 16);
        o.y = (unsigned int)f2bf(v0.z) | ((unsigned int)f2bf(v0.w) << 16);
        o.z = (unsigned int)f2bf(v1.x) | ((unsigned int)f2bf(v1.y) << 16);
        o.w = (unsigned int)f2bf(v1.z) | ((unsigned int)f2bf(v1.w) << 16);
        *reinterpret_cast<uint4*>(&xb[u * 8]) = o;
    }
}

// ---------------------------------------------------------------------------
// Kernel A: pack Wq[2048,256] | Wk[2048,64] | Ww[2048,4] -> WcatT[384][2048] bf16
// ---------------------------------------------------------------------------
__global__ __launch_bounds__(256) void pack_w(const float* __restrict__ Wq,
                                              const float* __restrict__ Wk,
                                              const float* __restrict__ Ww,
                                              unsigned short* __restrict__ WcatT) {
    const int n0 = blockIdx.x * 64;
    const int d0 = blockIdx.y * 64;
    __shared__ float tile[64][65];
    const int t = threadIdx.x;
#pragma unroll
    for (int i = 0; i < 16; ++i) {
        int flat = i * 256 + t;
        int r = flat >> 6;
        int c = flat & 63;
        int n = n0 + c, d = d0 + r;
        float v;
        if (n < NQ)            v = Wq[(size_t)d * NQ + n];
        else if (n < NQ + 64)  v = Wk[(size_t)d * DIdim + (n - NQ)];
        else if (n < NCAT)     v = Ww[(size_t)d * Hdim + (n - NQ - 64)];
        else                   v = 0.0f;
        tile[r][c] = v;
    }
    __syncthreads();
#pragma unroll
    for (int i = 0; i < 16; ++i) {
        int flat = i * 256 + t;
        int nn = flat >> 6;
        int dd = flat & 63;
        WcatT[(size_t)(n0 + nn) * Ddim + d0 + dd] = f2bf(tile[dd][nn]);
    }
}

// ---------------------------------------------------------------------------
// Kernel B2: QKW[8192][384] bf16 = xb[8192][2048] @ WcatT^T
// BM=32, BN=192 (2 n-tiles -> x read only 2x), BK=64, grid (2,256)=512 blocks
// (2 blocks/CU). global_load_lds 16B staging, pre-swizzled source + XOR read.
// ---------------------------------------------------------------------------
#define BM2 32
#define BN2 192
#define BK 64

__global__ __launch_bounds__(256) void proj_gemm2(const unsigned short* __restrict__ xb,
                                                  const unsigned short* __restrict__ WcatT,
                                                  unsigned short* __restrict__ QKW) {
    // A: [32][64] bf16 = 4KB at 0; B: [192][64] bf16 = 24KB at 4096
    __shared__ __align__(16) unsigned char lds[(BM2 + BN2) * BK * 2];
    const int n0 = blockIdx.x * BN2;
    const int m0 = blockIdx.y * BM2;
    const int tid = threadIdx.x;
    const int lane = tid & 63;
    const int wave = tid >> 6;           // 0..3, all-n split: wave tile 32x48
    const int lrow = lane & 15;
    const int kgrp = lane >> 4;

    f32x4 acc[2][3];
#pragma unroll
    for (int ts = 0; ts < 2; ++ts)
#pragma unroll
        for (int ns = 0; ns < 3; ++ns)
            acc[ts][ns] = (f32x4){0.f, 0.f, 0.f, 0.f};

    for (int k0 = 0; k0 < Ddim; k0 += BK) {
        __syncthreads();
        // stage A: 32 rows x 8 chunks = 256 chunks, 1/thread
        {
            int flat = tid;
            int r = flat >> 3, c = flat & 7;
            int cs = c ^ (r & 7);                       // pre-swizzled source
            gload16(&xb[(size_t)(m0 + r) * Ddim + k0 + cs * 8], &lds[flat * 16]);
        }
        // stage B: 192 rows x 8 chunks = 1536 chunks, 6/thread
#pragma unroll
        for (int i = 0; i < 6; ++i) {
            int flat = i * 256 + tid;
            int n = flat >> 3, c = flat & 7;
            int cs = c ^ (n & 7);
            gload16(&WcatT[(size_t)(n0 + n) * Ddim + k0 + cs * 8],
                    &lds[BM2 * BK * 2 + flat * 16]);
        }
        __syncthreads();
#pragma unroll
        for (int ks = 0; ks < 2; ++ks) {
            bf16x8 a[2], bb[3];
#pragma unroll
            for (int ts = 0; ts < 2; ++ts) {
                int r = ts * 16 + lrow;
                int c = (ks * 4 + kgrp) ^ (r & 7);      // swizzled read
                a[ts] = *reinterpret_cast<const bf16x8*>(&lds[r * 128 + c * 16]);
            }
#pragma unroll
            for (int ns = 0; ns < 3; ++ns) {
                int n = wave * 48 + ns * 16 + lrow;
                int c = (ks * 4 + kgrp) ^ (n & 7);
                bb[ns] = *reinterpret_cast<const bf16x8*>(
                    &lds[BM2 * BK * 2 + n * 128 + c * 16]);
            }
#pragma unroll
            for (int ts = 0; ts < 2; ++ts)
#pragma unroll
                for (int ns = 0; ns < 3; ++ns)
                    acc[ts][ns] = __builtin_amdgcn_mfma_f32_16x16x32_bf16(
                        a[ts], bb[ns], acc[ts][ns], 0, 0, 0);
        }
    }
#pragma unroll
    for (int ts = 0; ts < 2; ++ts)
#pragma unroll
        for (int ns = 0; ns < 3; ++ns)
#pragma unroll
            for (int j = 0; j < 4; ++j) {
                int r = m0 + ts * 16 + kgrp * 4 + j;
                int c = n0 + wave * 48 + ns * 16 + lrow;
                QKW[(size_t)r * NPAD + c] = f2bf(acc[ts][ns][j]);
            }
}

// ---------------------------------------------------------------------------
// Kernel B (fallback, ws too small): fused f32->bf16 staging, BM=128/BN=64
// ---------------------------------------------------------------------------
#define BMf 128
#define BNf 64
__global__ __launch_bounds__(256) void proj_gemm(const float* __restrict__ x,
                                                 const unsigned short* __restrict__ WcatT,
                                                 unsigned short* __restrict__ QKW) {
    __shared__ __align__(16) unsigned char lds[BMf * BK * 2 + BNf * BK * 2];
    const int m0 = blockIdx.y * BMf;
    const int n0 = blockIdx.x * BNf;
    const int tid = threadIdx.x;
    const int lane = tid & 63;
    const int wave = tid >> 6;
    f32x4 acc[2][4];
#pragma unroll
    for (int ts = 0; ts < 2; ++ts)
#pragma unroll
        for (int ns = 0; ns < 4; ++ns)
            acc[ts][ns] = (f32x4){0.f, 0.f, 0.f, 0.f};
    const int lrow = lane & 15;
    const int kgrp = lane >> 4;
    for (int k0 = 0; k0 < Ddim; k0 += BK) {
        __syncthreads();
#pragma unroll
        for (int i = 0; i < 8; ++i) {
            int flat = i * 256 + tid;
            int r = flat >> 4;
            int c4 = flat & 15;
            const float4 v = *reinterpret_cast<const float4*>(
                &x[(size_t)(m0 + r) * Ddim + k0 + c4 * 4]);
            unsigned int p0 = (unsigned int)f2bf(v.x) | ((unsigned int)f2bf(v.y) << 16);
            unsigned int p1 = (unsigned int)f2bf(v.z) | ((unsigned int)f2bf(v.w) << 16);
            int byte = r * 128 + c4 * 8;
            byte ^= (r & 7) << 4;
            *reinterpret_cast<uint2*>(&lds[byte]) = make_uint2(p0, p1);
        }
#pragma unroll
        for (int i = 0; i < 2; ++i) {
            int flat = i * 256 + tid;
            int n = flat >> 3;
            int k8 = flat & 7;
            const int4 v = *reinterpret_cast<const int4*>(
                &WcatT[(size_t)(n0 + n) * Ddim + k0 + k8 * 8]);
            int byte = n * 128 + k8 * 16;
            byte ^= (n & 7) << 4;
            *reinterpret_cast<int4*>(&lds[BMf * BK * 2 + byte]) = v;
        }
        __syncthreads();
#pragma unroll
        for (int ks = 0; ks < 2; ++ks) {
            bf16x8 a[2], bb[4];
#pragma unroll
            for (int ts = 0; ts < 2; ++ts) {
                int r = wave * 32 + ts * 16 + lrow;
                int byte = r * 128 + (ks * 32 + 8 * kgrp) * 2;
                byte ^= (r & 7) << 4;
                a[ts] = *reinterpret_cast<const bf16x8*>(&lds[byte]);
            }
#pragma unroll
            for (int ns = 0; ns < 4; ++ns) {
                int n = ns * 16 + lrow;
                int byte = n * 128 + (ks * 32 + 8 * kgrp) * 2;
                byte ^= (n & 7) << 4;
                bb[ns] = *reinterpret_cast<const bf16x8*>(&lds[BMf * BK * 2 + byte]);
            }
#pragma unroll
            for (int ts = 0; ts < 2; ++ts)
#pragma unroll
                for (int ns = 0; ns < 4; ++ns)
                    acc[ts][ns] = __builtin_amdgcn_mfma_f32_16x16x32_bf16(
                        a[ts], bb[ns], acc[ts][ns], 0, 0, 0);
        }
    }
#pragma unroll
    for (int ts = 0; ts < 2; ++ts)
#pragma unroll
        for (int ns = 0; ns < 4; ++ns)
#pragma unroll
            for (int j = 0; j < 4; ++j) {
                int r = m0 + wave * 32 + ts * 16 + kgrp * 4 + j;
                int c = n0 + ns * 16 + lrow;
                QKW[(size_t)r * NPAD + c] = f2bf(acc[ts][ns][j]);
            }
}

// ---------------------------------------------------------------------------
// Kernel C2: out[b][t][s] = sum_h w[b,t,h] * relu( Q[b,t,h,:] . K[b,s,:] )
// 128x128 tile, 8 waves (4t x 2s), wave tile 32x64. Operands from global
// (QKW 6.3MB, L2-resident). Non-temporal stores keep QKW in L2.
// ---------------------------------------------------------------------------
__global__ __launch_bounds__(512) void indexer2(const unsigned short* __restrict__ QKW,
                                                float* __restrict__ out) {
    const int st = blockIdx.x;
    const int tt = blockIdx.y;
    const int b  = blockIdx.z;
    const int tid = threadIdx.x;
    const int lane = tid & 63;
    const int wave = tid >> 6;           // 0..7
    const int wt  = wave >> 1;           // 0..3  (t sub-tile)
    const int wsb = wave & 1;            // 0..1  (s sub-tile)
    const int lrow = lane & 15;
    const int kgrp = lane >> 4;
    const int kcol = 8 * kgrp;
    const size_t rowBase = (size_t)b * Tdim;

    // K fragments for this wave's 64 s-rows
    bf16x8 kf[4][2];
#pragma unroll
    for (int ss = 0; ss < 4; ++ss)
#pragma unroll
        for (int ks = 0; ks < 2; ++ks) {
            size_t row = rowBase + st * 128 + wsb * 64 + ss * 16 + lrow;
            kf[ss][ks] = *reinterpret_cast<const bf16x8*>(
                &QKW[row * NPAD + NQ + ks * 32 + kcol]);
        }

    // Q fragments for all heads (this wave's 32 t-rows)
    bf16x8 qf[4][2][2];                  // [h][ts][ks]
#pragma unroll
    for (int h = 0; h < Hdim; ++h)
#pragma unroll
        for (int ts = 0; ts < 2; ++ts)
#pragma unroll
            for (int ks = 0; ks < 2; ++ks) {
                size_t row = rowBase + tt * 128 + wt * 32 + ts * 16 + lrow;
                qf[h][ts][ks] = *reinterpret_cast<const bf16x8*>(
                    &QKW[row * NPAD + h * DIdim + ks * 32 + kcol]);
            }

    // per-head weights for this lane's 8 output rows (one 8B load per row)
    float wreg[2][4][4];                 // [ts][j][h]
#pragma unroll
    for (int ts = 0; ts < 2; ++ts)
#pragma unroll
        for (int j = 0; j < 4; ++j) {
            int t = tt * 128 + wt * 32 + ts * 16 + kgrp * 4 + j;
            const uint2 wp = *reinterpret_cast<const uint2*>(
                &QKW[(rowBase + t) * NPAD + NQ + 64]);
            wreg[ts][j][0] = bf2f((unsigned short)(wp.x & 0xffff));
            wreg[ts][j][1] = bf2f((unsigned short)(wp.x >> 16));
            wreg[ts][j][2] = bf2f((unsigned short)(wp.y & 0xffff));
            wreg[ts][j][3] = bf2f((unsigned short)(wp.y >> 16));
        }

    f32x4 oacc[2][4];
#pragma unroll
    for (int ts = 0; ts < 2; ++ts)
#pragma unroll
        for (int ss = 0; ss < 4; ++ss)
            oacc[ts][ss] = (f32x4){0.f, 0.f, 0.f, 0.f};

#pragma unroll
    for (int ss = 0; ss < 4; ++ss)
#pragma unroll
        for (int h = 0; h < Hdim; ++h) {
            f32x4 d[2];
            d[0] = (f32x4){0.f, 0.f, 0.f, 0.f};
            d[1] = (f32x4){0.f, 0.f, 0.f, 0.f};
#pragma unroll
            for (int ks = 0; ks < 2; ++ks)
#pragma unroll
                for (int ts = 0; ts < 2; ++ts)
                    d[ts] = __builtin_amdgcn_mfma_f32_16x16x32_bf16(
                        qf[h][ts][ks], kf[ss][ks], d[ts], 0, 0, 0);
#pragma unroll
            for (int ts = 0; ts < 2; ++ts)
#pragma unroll
                for (int j = 0; j < 4; ++j)
                    oacc[ts][ss][j] = fmaf(wreg[ts][j][h], fmaxf(d[ts][j], 0.f),
                                           oacc[ts][ss][j]);
        }

#pragma unroll
    for (int ts = 0; ts < 2; ++ts)
#pragma unroll
        for (int ss = 0; ss < 4; ++ss)
#pragma unroll
            for (int j = 0; j < 4; ++j) {
                int t = tt * 128 + wt * 32 + ts * 16 + kgrp * 4 + j;
                int s = st * 128 + wsb * 64 + ss * 16 + lrow;
                __builtin_nontemporal_store(oacc[ts][ss][j],
                                            &out[(rowBase + t) * Tdim + s]);
            }
}

// ---------------------------------------------------------------------------
extern "C" void kernel_launch(void* const* d_in, const int* in_sizes, int n_in,
                              void* d_out, int out_size, void* d_ws, size_t ws_size,
                              hipStream_t stream) {
    const float* x  = (const float*)d_in[0];
    const float* Wq = (const float*)d_in[1];
    const float* Wk = (const float*)d_in[2];
    const float* Ww = (const float*)d_in[3];
    float* out = (float*)d_out;

    unsigned short* WcatT = (unsigned short*)d_ws;                       // 1.5MB
    unsigned short* QKW   = (unsigned short*)((char*)d_ws + (size_t)NPAD * Ddim * 2);
    const size_t qkw_bytes = (size_t)Mdim * NPAD * 2;                    // 6.3MB
    unsigned short* xb = (unsigned short*)((char*)QKW + qkw_bytes);      // 33.5MB
    const size_t need = (size_t)NPAD * Ddim * 2 + qkw_bytes + (size_t)Mdim * Ddim * 2;

    pack_w<<<dim3(NPAD / 64, Ddim / 64), 256, 0, stream>>>(Wq, Wk, Ww, WcatT);
    if (ws_size >= need) {
        convert_x<<<2048, 256, 0, stream>>>(x, xb);
        proj_gemm2<<<dim3(NPAD / BN2, Mdim / BM2), 256, 0, stream>>>(xb, WcatT, QKW);
    } else {
        proj_gemm<<<dim3(NPAD / BNf, Mdim / BMf), 256, 0, stream>>>(x, WcatT, QKW);
    }
    indexer2<<<dim3(Tdim / 128, Tdim / 128, Bdim), 512, 0, stream>>>(QKW, out);
}

// Round 3
// 250.307 us; speedup vs baseline: 1.0538x; 1.0538x over previous
//
#include <hip/hip_runtime.h>
#include <hip/hip_bf16.h>

#define Bdim 2
#define Tdim 4096
#define Ddim 2048
#define Hdim 4
#define DIdim 64
#define NQ 256          // H*DI
#define NCAT 324        // 256 + 64 + 4
#define NPAD 384        // padded N for the projection GEMM
#define Mdim 8192       // B*T

typedef __attribute__((ext_vector_type(8))) short bf16x8;
typedef __attribute__((ext_vector_type(4))) float f32x4;

__device__ __forceinline__ unsigned short f2bf(float f) {
    unsigned int u = __builtin_bit_cast(unsigned int, f);
    u += 0x7fffu + ((u >> 16) & 1u);          // round-to-nearest-even
    return (unsigned short)(u >> 16);
}
__device__ __forceinline__ float bf2f(unsigned short h) {
    unsigned int u = ((unsigned int)h) << 16;
    return __builtin_bit_cast(float, u);
}
// packed-bf16x4 (uint2) -> float for compile-time h after unroll
__device__ __forceinline__ float wget(uint2 w, int h) {
    unsigned int u = (h & 2) ? w.y : w.x;
    unsigned int v = (h & 1) ? (u & 0xffff0000u) : (u << 16);
    return __builtin_bit_cast(float, v);
}

// async 16B global->LDS (direct-to-LDS DMA; dest = wave-uniform base + lane*16)
__device__ __forceinline__ void gload16(const void* g, void* l) {
    __builtin_amdgcn_global_load_lds(
        (const __attribute__((address_space(1))) unsigned int*)g,
        (__attribute__((address_space(3))) unsigned int*)l, 16, 0, 0);
}

// ---------------------------------------------------------------------------
// Kernel 0: x f32 -> bf16 (one-time), 100MB traffic, BW-bound (~16us)
// ---------------------------------------------------------------------------
__global__ __launch_bounds__(256) void convert_x(const float* __restrict__ x,
                                                 unsigned short* __restrict__ xb) {
    const size_t N8 = (size_t)Mdim * Ddim / 8;
    for (size_t u = (size_t)blockIdx.x * 256 + threadIdx.x; u < N8;
         u += (size_t)gridDim.x * 256) {
        const float4 v0 = *reinterpret_cast<const float4*>(&x[u * 8]);
        const float4 v1 = *reinterpret_cast<const float4*>(&x[u * 8 + 4]);
        uint4 o;
        o.x = (unsigned int)f2bf(v0.x) | ((unsigned int)f2bf(v0.y) << 16);
        o.y = (unsigned int)f2bf(v0.z) | ((unsigned int)f2bf(v0.w) << 16);
        o.z = (unsigned int)f2bf(v1.x) | ((unsigned int)f2bf(v1.y) << 16);
        o.w = (unsigned int)f2bf(v1.z) | ((unsigned int)f2bf(v1.w) << 16);
        *reinterpret_cast<uint4*>(&xb[u * 8]) = o;
    }
}

// ---------------------------------------------------------------------------
// Kernel A: pack Wq[2048,256] | Wk[2048,64] | Ww[2048,4] -> WcatT[384][2048] bf16
// ---------------------------------------------------------------------------
__global__ __launch_bounds__(256) void pack_w(const float* __restrict__ Wq,
                                              const float* __restrict__ Wk,
                                              const float* __restrict__ Ww,
                                              unsigned short* __restrict__ WcatT) {
    const int n0 = blockIdx.x * 64;
    const int d0 = blockIdx.y * 64;
    __shared__ float tile[64][65];
    const int t = threadIdx.x;
#pragma unroll
    for (int i = 0; i < 16; ++i) {
        int flat = i * 256 + t;
        int r = flat >> 6;
        int c = flat & 63;
        int n = n0 + c, d = d0 + r;
        float v;
        if (n < NQ)            v = Wq[(size_t)d * NQ + n];
        else if (n < NQ + 64)  v = Wk[(size_t)d * DIdim + (n - NQ)];
        else if (n < NCAT)     v = Ww[(size_t)d * Hdim + (n - NQ - 64)];
        else                   v = 0.0f;
        tile[r][c] = v;
    }
    __syncthreads();
#pragma unroll
    for (int i = 0; i < 16; ++i) {
        int flat = i * 256 + t;
        int nn = flat >> 6;
        int dd = flat & 63;
        WcatT[(size_t)(n0 + nn) * Ddim + d0 + dd] = f2bf(tile[dd][nn]);
    }
}

// ---------------------------------------------------------------------------
// Kernel B3: QKW[8192][384] = xb @ WcatT^T.  BM=32, BN=192, BK=64.
// 512 threads (8 waves = 2M x 4N), double-buffered LDS, 2-phase pipeline:
// STAGE(next) issued before compute(cur), one barrier per K-step (T3-minimum).
// global_load_lds 16B, linear LDS dest + inverse-swizzled source + swz read.
// ---------------------------------------------------------------------------
#define PBM 32
#define PBN 192
#define PBK 64
#define ABYTES (PBM * PBK * 2)            // 4 KB
#define BBYTES (PBN * PBK * 2)            // 24 KB
#define BUFBYTES (ABYTES + BBYTES)        // 28 KB

__global__ __launch_bounds__(512) void proj_gemm3(const unsigned short* __restrict__ xb,
                                                  const unsigned short* __restrict__ WcatT,
                                                  unsigned short* __restrict__ QKW) {
    __shared__ __align__(16) unsigned char lds[2 * BUFBYTES];
    const int n0 = blockIdx.x * PBN;
    const int m0 = blockIdx.y * PBM;
    const int tid = threadIdx.x;
    const int lane = tid & 63;
    const int wm = (tid >> 6) >> 2;       // 0..1 (16 t-rows each)
    const int wn = (tid >> 6) & 3;        // 0..3 (48 n-cols each)
    const int lrow = lane & 15;
    const int kgrp = lane >> 4;

    f32x4 acc[3];
#pragma unroll
    for (int ns = 0; ns < 3; ++ns) acc[ns] = (f32x4){0.f, 0.f, 0.f, 0.f};

    auto stage = [&](unsigned char* buf, int k0) {
        if (tid < 256) {                            // A: 32 rows x 8 chunks
            int r = tid >> 3, c = tid & 7;
            int cs = c ^ (r & 7);
            gload16(&xb[(size_t)(m0 + r) * Ddim + k0 + cs * 8], buf + tid * 16);
        }
#pragma unroll
        for (int i = 0; i < 3; ++i) {               // B: 192 rows x 8 chunks
            int flat = i * 512 + tid;
            int n = flat >> 3, c = flat & 7;
            int cs = c ^ (n & 7);
            gload16(&WcatT[(size_t)(n0 + n) * Ddim + k0 + cs * 8],
                    buf + ABYTES + flat * 16);
        }
    };

    stage(lds, 0);
    __syncthreads();
    int cur = 0;
    for (int k0 = 0; k0 < Ddim; k0 += PBK) {
        unsigned char* bc = lds + cur * BUFBYTES;
        unsigned char* bn = lds + (cur ^ 1) * BUFBYTES;
        if (k0 + PBK < Ddim) stage(bn, k0 + PBK);   // prefetch next tile
#pragma unroll
        for (int ks = 0; ks < 2; ++ks) {
            int r = wm * 16 + lrow;
            int ca = (ks * 4 + kgrp) ^ (r & 7);
            bf16x8 a = *reinterpret_cast<const bf16x8*>(bc + r * 128 + ca * 16);
            bf16x8 bb[3];
#pragma unroll
            for (int ns = 0; ns < 3; ++ns) {
                int n = wn * 48 + ns * 16 + lrow;
                int cb = (ks * 4 + kgrp) ^ (n & 7);
                bb[ns] = *reinterpret_cast<const bf16x8*>(bc + ABYTES + n * 128 + cb * 16);
            }
#pragma unroll
            for (int ns = 0; ns < 3; ++ns)
                acc[ns] = __builtin_amdgcn_mfma_f32_16x16x32_bf16(a, bb[ns], acc[ns], 0, 0, 0);
        }
        __syncthreads();                            // buf(cur^1) staged + buf(cur) free
        cur ^= 1;
    }
#pragma unroll
    for (int ns = 0; ns < 3; ++ns)
#pragma unroll
        for (int j = 0; j < 4; ++j) {
            int r = m0 + wm * 16 + kgrp * 4 + j;
            int c = n0 + wn * 48 + ns * 16 + lrow;
            QKW[(size_t)r * NPAD + c] = f2bf(acc[ns][j]);
        }
}

// ---------------------------------------------------------------------------
// Kernel C3: out[b][t][s] = sum_h w[b,t,h] * relu( Q[b,t,h,:] . K[b,s,:] )
// 128x128 tile, 8 waves (4t x 2s). K tile staged ONCE into swizzled LDS
// (16 KB); Q streamed per-head from global (L2-hot); weights kept packed.
// Low VGPR (~110) -> 3-4 waves/SIMD for latency hiding. NT stores.
// ---------------------------------------------------------------------------
__global__ __launch_bounds__(512) void indexer3(const unsigned short* __restrict__ QKW,
                                                float* __restrict__ out) {
    __shared__ __align__(16) unsigned char klds[128 * 128];   // 128 rows x 64 bf16
    const int st = blockIdx.x;
    const int tt = blockIdx.y;
    const int b  = blockIdx.z;
    const int tid = threadIdx.x;
    const int lane = tid & 63;
    const int wave = tid >> 6;            // 0..7
    const int wt  = wave >> 1;            // 0..3  (32 t-rows)
    const int wsb = wave & 1;             // 0..1  (64 s-rows)
    const int lrow = lane & 15;
    const int kgrp = lane >> 4;
    const int kcol = 8 * kgrp;
    const size_t rowBase = (size_t)b * Tdim;

    // ---- stage K tile: 128 rows x 8 chunks of 16B, 2 per thread, swizzled
#pragma unroll
    for (int i = 0; i < 2; ++i) {
        int flat = i * 512 + tid;
        int r = flat >> 3, c = flat & 7;
        int cs = c ^ (r & 7);
        gload16(&QKW[(rowBase + st * 128 + r) * NPAD + NQ + cs * 8], &klds[flat * 16]);
    }

    // ---- packed per-head weights for this lane's 8 output rows
    uint2 wpk[2][4];
#pragma unroll
    for (int ts = 0; ts < 2; ++ts)
#pragma unroll
        for (int j = 0; j < 4; ++j) {
            int trow = tt * 128 + wt * 32 + ts * 16 + kgrp * 4 + j;
            wpk[ts][j] = *reinterpret_cast<const uint2*>(
                &QKW[(rowBase + trow) * NPAD + NQ + 64]);
        }

    f32x4 oacc[2][4];
#pragma unroll
    for (int ts = 0; ts < 2; ++ts)
#pragma unroll
        for (int ss = 0; ss < 4; ++ss)
            oacc[ts][ss] = (f32x4){0.f, 0.f, 0.f, 0.f};

    __syncthreads();                      // K tile resident (drains vmcnt)

    const size_t qrow0 = rowBase + tt * 128 + wt * 32;
#pragma unroll
    for (int h = 0; h < Hdim; ++h) {
        bf16x8 qf[2][2];
#pragma unroll
        for (int ts = 0; ts < 2; ++ts)
#pragma unroll
            for (int ks = 0; ks < 2; ++ks)
                qf[ts][ks] = *reinterpret_cast<const bf16x8*>(
                    &QKW[(qrow0 + ts * 16 + lrow) * NPAD + h * DIdim + ks * 32 + kcol]);
#pragma unroll
        for (int ss = 0; ss < 4; ++ss) {
            int rr = wsb * 64 + ss * 16 + lrow;
            bf16x8 kf[2];
#pragma unroll
            for (int ks = 0; ks < 2; ++ks)
                kf[ks] = *reinterpret_cast<const bf16x8*>(
                    &klds[rr * 128 + ((ks * 4 + kgrp) ^ (rr & 7)) * 16]);
            f32x4 d[2];
            d[0] = (f32x4){0.f, 0.f, 0.f, 0.f};
            d[1] = (f32x4){0.f, 0.f, 0.f, 0.f};
            __builtin_amdgcn_s_setprio(1);
#pragma unroll
            for (int ks = 0; ks < 2; ++ks)
#pragma unroll
                for (int ts = 0; ts < 2; ++ts)
                    d[ts] = __builtin_amdgcn_mfma_f32_16x16x32_bf16(
                        qf[ts][ks], kf[ks], d[ts], 0, 0, 0);
            __builtin_amdgcn_s_setprio(0);
#pragma unroll
            for (int ts = 0; ts < 2; ++ts)
#pragma unroll
                for (int j = 0; j < 4; ++j)
                    oacc[ts][ss][j] = fmaf(wget(wpk[ts][j], h),
                                           fmaxf(d[ts][j], 0.f), oacc[ts][ss][j]);
        }
    }

#pragma unroll
    for (int ts = 0; ts < 2; ++ts)
#pragma unroll
        for (int ss = 0; ss < 4; ++ss)
#pragma unroll
            for (int j = 0; j < 4; ++j) {
                int t = tt * 128 + wt * 32 + ts * 16 + kgrp * 4 + j;
                int s = st * 128 + wsb * 64 + ss * 16 + lrow;
                __builtin_nontemporal_store(oacc[ts][ss][j],
                                            &out[(rowBase + t) * Tdim + s]);
            }
}

// ---------------------------------------------------------------------------
extern "C" void kernel_launch(void* const* d_in, const int* in_sizes, int n_in,
                              void* d_out, int out_size, void* d_ws, size_t ws_size,
                              hipStream_t stream) {
    const float* x  = (const float*)d_in[0];
    const float* Wq = (const float*)d_in[1];
    const float* Wk = (const float*)d_in[2];
    const float* Ww = (const float*)d_in[3];
    float* out = (float*)d_out;

    unsigned short* WcatT = (unsigned short*)d_ws;                       // 1.5MB
    unsigned short* QKW   = (unsigned short*)((char*)d_ws + (size_t)NPAD * Ddim * 2);
    const size_t qkw_bytes = (size_t)Mdim * NPAD * 2;                    // 6.3MB
    unsigned short* xb = (unsigned short*)((char*)QKW + qkw_bytes);      // 33.5MB

    convert_x<<<2048, 256, 0, stream>>>(x, xb);
    pack_w<<<dim3(NPAD / 64, Ddim / 64), 256, 0, stream>>>(Wq, Wk, Ww, WcatT);
    proj_gemm3<<<dim3(NPAD / PBN, Mdim / PBM), 512, 0, stream>>>(xb, WcatT, QKW);
    indexer3<<<dim3(Tdim / 128, Tdim / 128, Bdim), 512, 0, stream>>>(QKW, out);
}